// Round 6
// baseline (270.774 us; speedup 1.0000x reference)
//
#include <hip/hip_runtime.h>
#include <math.h>

// ISTFT via register-resident packed real inverse FFT + LDS overlap-add.
//   B=16, T=2048, 513 bins, FFT=1024, HOP=256, out = 16 x 525056 (= 2051*256).
//   Pack (R5-verified): Z[k] = (Y[k]+C[k]) + i*W1024^k*(Y[k]-C[k]),
//     C[0]=Y[512], C[k]=conj(Y[512-k]); DC/Nyquist imag parts zeroed.
//   IDFT_512 = 8(within-lane) x 64(cross-lane):
//     u_l[m] = sum_q Z[l+64q] W8^{mq}          (in-register 8-pt, const twiddles)
//     v_l[m] = u_l[m] * e^{2pi i m l/512}      (hoisted powers)
//     z[8t+m] = sum_l v_l[m] W64^{tl}          (6 shfl_xor DIF stages, t=bitrev6(lane))
//   Lane ends holding 16 contiguous samples at n0 = 16*bitrev6(lane):
//   window (hoisted, lane-fixed) + ds_add into padded OLA, then plain store.

#define BATCH  16
#define TFR    2048
#define NB     513
#define HOP    256
#define OUTLEN 525056
#define TROWS  2051
#define OWN    32
#define NBLK   65                         // ceil(2051/32)
#define OLALEN (OWN * HOP)                // 8192
#define OLAPAD (OLALEN + OLALEN / 16)     // 8704 floats = 34.8 KB

#define PIDX(n) ((n) + ((n) >> 4))

#define TWO_PI 6.2831853071795864f
#define WSCALE 8.456302966727588e-4f      // (sqrt(3)/2) / 1024

__device__ __forceinline__ float2 cadd(float2 a, float2 b){ return make_float2(a.x+b.x, a.y+b.y); }
__device__ __forceinline__ float2 csub(float2 a, float2 b){ return make_float2(a.x-b.x, a.y-b.y); }
__device__ __forceinline__ float2 cmul(float2 a, float2 b){ return make_float2(a.x*b.x - a.y*b.y, a.x*b.y + a.y*b.x); }

__global__ __launch_bounds__(256)
void istft_rfft(const float2* __restrict__ stfts, float* __restrict__ out)
{
    __shared__ float ola[OLAPAD];

    const int tid  = threadIdx.x;
    const int lane = tid & 63;
    const int wave = tid >> 6;

    const int b  = blockIdx.x / NBLK;
    const int ib = blockIdx.x - b * NBLK;
    const int T0 = ib * OWN;

    for (int i = tid; i < OLAPAD; i += 256) ola[i] = 0.f;

    // ---- hoisted per-lane constants (all frame-invariant) ----
    // pack twiddles W1024^{lane+64r}
    float2 ptw[8];
    #pragma unroll
    for (int r = 0; r < 8; ++r) {
        float s, c;
        sincosf(TWO_PI * (float)(lane + 64 * r) * (1.0f / 1024.0f), &s, &c);
        ptw[r] = make_float2(c, s);
    }
    // step-2 twiddles om[m] = e^{+2pi i lane*m/512}
    float2 om[8];
    om[0] = make_float2(1.f, 0.f);
    { float s, c; sincosf(TWO_PI * (float)lane * (1.0f / 512.0f), &s, &c); om[1] = make_float2(c, s); }
    #pragma unroll
    for (int m = 2; m < 8; ++m) om[m] = cmul(om[m - 1], om[1]);
    // DIF stage twiddles (merged with identity for lower lanes), h = 32,16,8,4,2
    float2 twc[5];
    #pragma unroll
    for (int s = 0; s < 5; ++s) {
        const int h = 32 >> s;
        float sn, cs;
        sincosf(TWO_PI * (float)(lane & (h - 1)) / (float)(2 * h), &sn, &cs);
        twc[s] = (lane & h) ? make_float2(cs, sn) : make_float2(1.f, 0.f);
    }
    // output ordering + window (lane-fixed: lane holds samples n0..n0+15)
    const int brl = ((lane & 1) << 5) | ((lane & 2) << 3) | ((lane & 4) << 1)
                  | ((lane & 8) >> 1) | ((lane & 16) >> 3) | ((lane & 32) >> 5);
    const int n0 = brl * 16;
    float win[16];
    #pragma unroll
    for (int j = 0; j < 16; ++j)
        win[j] = (0.5f - 0.5f * cosf(TWO_PI * (float)(n0 + j) * (1.0f / 1024.0f))) * WSCALE;

    __syncthreads();   // ola zeroed

    const int tmin = (T0 - 3 > 0) ? T0 - 3 : 0;
    const int tmax = (T0 + OWN - 1 < TFR - 1) ? T0 + OWN - 1 : TFR - 1;
    const int srcl = (64 - lane) & 63;

    for (int t = tmin + wave; t <= tmax; t += 4) {
        const float2* Xg = stfts + (size_t)(b * TFR + t) * NB;

        // load X[0..511] into regs (coalesced 8B/lane) + X[512]
        float2 X[8];
        #pragma unroll
        for (int r = 0; r < 8; ++r) X[r] = Xg[lane + 64 * r];
        const float2 X512 = Xg[512];

        // hermitian pack -> Z (k = lane + 64r; mirror from lane 64-lane, reg 7-r)
        float2 Z[8];
        #pragma unroll
        for (int r = 0; r < 8; ++r) {
            float2 mv;
            mv.x = __shfl(X[7 - r].x, srcl);
            mv.y = __shfl(X[7 - r].y, srcl);
            const float2 fix = (r == 0) ? X512 : X[(8 - r) & 7];   // lane-0 correction
            if (lane == 0) mv = fix;
            float Yy = X[r].y, Cy = -mv.y;
            if (lane == 0 && r == 0) { Yy = 0.f; Cy = 0.f; }       // DC/Nyquist imag -> 0
            const float Sx = X[r].x + mv.x, Sy = Yy + Cy;
            const float Dx = X[r].x - mv.x, Dy = Yy - Cy;
            const float2 W = ptw[r];
            const float ex = W.x * Dx - W.y * Dy;
            const float ey = W.x * Dy + W.y * Dx;
            Z[r] = make_float2(Sx - ey, Sy + ex);
        }

        // within-lane 8-pt inverse DFT over r (u[m] = sum_q Z[q] W8^{mq})
        float2 u[8];
        {
            const float2 t0 = cadd(Z[0], Z[4]), t1 = csub(Z[0], Z[4]);
            const float2 t2 = cadd(Z[2], Z[6]), t3 = csub(Z[2], Z[6]);
            const float2 t4 = cadd(Z[1], Z[5]), t5 = csub(Z[1], Z[5]);
            const float2 t6 = cadd(Z[3], Z[7]), t7 = csub(Z[3], Z[7]);
            const float2 E0 = cadd(t0, t2), E2 = csub(t0, t2);
            const float2 E1 = make_float2(t1.x - t3.y, t1.y + t3.x);   // t1 + i t3
            const float2 E3 = make_float2(t1.x + t3.y, t1.y - t3.x);   // t1 - i t3
            const float2 O0 = cadd(t4, t6), O2 = csub(t4, t6);
            const float2 O1 = make_float2(t5.x - t7.y, t5.y + t7.x);
            const float2 O3 = make_float2(t5.x + t7.y, t5.y - t7.x);
            const float cc = 0.70710678118654752f;
            const float2 W1O1 = make_float2(cc * (O1.x - O1.y), cc * (O1.x + O1.y));
            const float2 iO2  = make_float2(-O2.y, O2.x);
            const float2 W3O3 = make_float2(cc * (-O3.x - O3.y), cc * (O3.x - O3.y));
            u[0] = cadd(E0, O0);   u[4] = csub(E0, O0);
            u[1] = cadd(E1, W1O1); u[5] = csub(E1, W1O1);
            u[2] = cadd(E2, iO2);  u[6] = csub(E2, iO2);
            u[3] = cadd(E3, W3O3); u[7] = csub(E3, W3O3);
        }
        #pragma unroll
        for (int m = 1; m < 8; ++m) u[m] = cmul(u[m], om[m]);

        // 64-pt inverse DFT across lanes: 6 DIF stages (h = 32..1)
        #pragma unroll
        for (int s = 0; s < 6; ++s) {
            const int h = 32 >> s;
            const bool lo = (lane & h) == 0;
            #pragma unroll
            for (int m = 0; m < 8; ++m) {
                const float sx = __shfl_xor(u[m].x, h);
                const float sy = __shfl_xor(u[m].y, h);
                float2 w;
                w.x = sx + (lo ? u[m].x : -u[m].x);
                w.y = sy + (lo ? u[m].y : -u[m].y);
                u[m] = (h > 1) ? cmul(w, twc[s]) : w;
            }
        }

        // lane holds z[8*brl + m] -> samples n0+2m, n0+2m+1; window + OLA
        const int base = (t - T0) * HOP + n0;       // 16-aligned chunk
        if ((unsigned)base < OLALEN) {
            const int pb = PIDX(base);              // chunk contiguous after padding
            #pragma unroll
            for (int m = 0; m < 8; ++m) {
                atomicAdd(&ola[pb + 2 * m],     u[m].x * win[2 * m]);
                atomicAdd(&ola[pb + 2 * m + 1], u[m].y * win[2 * m + 1]);
            }
        }
    }

    __syncthreads();

    // plain-store exclusive region (every out element written exactly once)
    const int ownRows = (TROWS - T0 < OWN) ? (TROWS - T0) : OWN;
    const int total   = ownRows * HOP;
    float* og = out + (size_t)b * OUTLEN + (size_t)T0 * HOP;
    for (int i = tid; i < total; i += 256)
        og[i] = ola[PIDX(i)];
}

extern "C" void kernel_launch(void* const* d_in, const int* in_sizes, int n_in,
                              void* d_out, int out_size, void* d_ws, size_t ws_size,
                              hipStream_t stream)
{
    const float2* stfts = reinterpret_cast<const float2*>(d_in[0]);
    float* out = reinterpret_cast<float*>(d_out);

    istft_rfft<<<dim3(BATCH * NBLK), dim3(256), 0, stream>>>(stfts, out);
}